// Round 1
// baseline (66.759 us; speedup 1.0000x reference)
//
#include <hip/hip_runtime.h>

// Memristor dense fwd, algebraically simplified:
//   t[b,r]   = max(2*|x[b,r]|, 1e-12)            (bias row: t=2)
//   s[b,r]   = sign(x[b,r])
//   gp/gn    = log2(n_param[r, 2j]/[r, 2j+1])
//   q        = max_w / 9      (max_w = max over combined weights incl. bias)
//   y[b,j]   = 0.5 * sum_r s * [ (w_p+q)*2^(log2(t)*gp) - (w_n+q)*2^(log2(t)*gn) ]

#define TB 16
#define TJ 16
#define RC 64
#define N_IN 1024
#define N_OUT 512
#define BDIM 128

__global__ void init_ws_kernel(unsigned int* ws) {
    ws[0] = __float_as_uint(0.5f);   // bias weights are part of the max
}

__global__ void zero_out_kernel(float* out) {
    out[blockIdx.x * 256 + threadIdx.x] = 0.0f;
}

__global__ void max_kernel(const float* __restrict__ wp, const float* __restrict__ wn,
                           const float* __restrict__ bp, const float* __restrict__ bn,
                           unsigned int* __restrict__ ws) {
    const int NW4 = (N_IN * N_OUT) / 4;   // float4 count
    int i = blockIdx.x * blockDim.x + threadIdx.x;
    int stride = gridDim.x * blockDim.x;
    float m = 0.0f;
    const float4* wp4 = (const float4*)wp;
    const float4* wn4 = (const float4*)wn;
    for (int idx = i; idx < NW4; idx += stride) {
        float4 a = wp4[idx];
        float4 b = wn4[idx];
        m = fmaxf(m, fmaxf(fmaxf(a.x, a.y), fmaxf(a.z, a.w)));
        m = fmaxf(m, fmaxf(fmaxf(b.x, b.y), fmaxf(b.z, b.w)));
    }
    if (i < N_OUT) {
        m = fmaxf(m, bp[i]);
        m = fmaxf(m, bn[i]);
    }
    // wave64 butterfly reduce
    #pragma unroll
    for (int off = 32; off > 0; off >>= 1)
        m = fmaxf(m, __shfl_xor(m, off));
    if ((threadIdx.x & 63) == 0)
        atomicMax(ws, __float_as_uint(m));   // all values >= 0 -> uint order == float order
}

__launch_bounds__(256, 4)
__global__ void memristor_main(const float* __restrict__ x,
                               const float* __restrict__ wp,
                               const float* __restrict__ wn,
                               const float* __restrict__ bp,
                               const float* __restrict__ bn,
                               const float* __restrict__ npar,
                               const unsigned int* __restrict__ ws,
                               float* __restrict__ out) {
    // L: (lr2, sign) per (b_local, r_local); padded row (65 pairs) to spread banks
    __shared__ float L[TB][RC + 1][2];
    __shared__ float W[RC][TJ][2];    // (w_pos+q, w_neg+q)
    __shared__ float Gm[RC][TJ][2];   // (gamma_pos, gamma_neg)

    const float maxw = __uint_as_float(ws[0]);
    const float q = maxw * (1.0f / 9.0f);

    const int j0 = blockIdx.x * TJ;
    const int b0 = blockIdx.y * TB;
    const int r_begin = blockIdx.z * 256;

    const int tid = threadIdx.x;
    const int tj = tid & 15;
    const int tb = tid >> 4;

    float acc = 0.0f;

    for (int r0 = r_begin; r0 < r_begin + 256; r0 += RC) {
        __syncthreads();   // protect LDS reuse from previous chunk
        // ---- stage (lr2, sign): 16 b-rows x 64 r's. One float4 of x per thread.
        {
            int bb = tid >> 4;
            int qd = tid & 15;
            float4 v = *(const float4*)&x[(b0 + bb) * N_IN + r0 + qd * 4];
            float vv[4] = {v.x, v.y, v.z, v.w};
            #pragma unroll
            for (int k = 0; k < 4; ++k) {
                float val = vv[k];
                float s = (val > 0.0f) ? 1.0f : ((val < 0.0f) ? -1.0f : 0.0f);
                float t = fmaxf(2.0f * fabsf(val), 1e-12f);
                L[bb][qd * 4 + k][0] = __builtin_amdgcn_logf(t);   // log2(t)
                L[bb][qd * 4 + k][1] = s;
            }
        }
        // ---- stage W (w+q) and Gm (log2(n)): 64 r-rows x 16 j's each
        {
            int rr = tid >> 2;
            int qd = tid & 3;
            float4 p = *(const float4*)&wp[(r0 + rr) * N_OUT + j0 + qd * 4];
            float4 n = *(const float4*)&wn[(r0 + rr) * N_OUT + j0 + qd * 4];
            float pv[4] = {p.x, p.y, p.z, p.w};
            float nv[4] = {n.x, n.y, n.z, n.w};
            #pragma unroll
            for (int k = 0; k < 4; ++k) {
                W[rr][qd * 4 + k][0] = pv[k] + q;
                W[rr][qd * 4 + k][1] = nv[k] + q;
            }
            #pragma unroll
            for (int it = 0; it < 2; ++it) {
                int qq = qd + it * 4;   // 0..7: which float4 of the 32-col row segment
                float4 g = *(const float4*)&npar[(r0 + rr) * (2 * N_OUT) + j0 * 2 + qq * 4];
                Gm[rr][qq * 2 + 0][0] = __builtin_amdgcn_logf(g.x);
                Gm[rr][qq * 2 + 0][1] = __builtin_amdgcn_logf(g.y);
                Gm[rr][qq * 2 + 1][0] = __builtin_amdgcn_logf(g.z);
                Gm[rr][qq * 2 + 1][1] = __builtin_amdgcn_logf(g.w);
            }
        }
        __syncthreads();
        // ---- compute: 64 r-steps, 2 exp2 each
        #pragma unroll 8
        for (int rr = 0; rr < RC; ++rr) {
            float lr2 = L[tb][rr][0];
            float s   = L[tb][rr][1];
            float wqp = W[rr][tj][0];
            float wqn = W[rr][tj][1];
            float gp  = Gm[rr][tj][0];
            float gn  = Gm[rr][tj][1];
            float ep = __builtin_amdgcn_exp2f(lr2 * gp);
            float en = __builtin_amdgcn_exp2f(lr2 * gn);
            acc += s * (wqp * ep - wqn * en);
        }
    }

    // bias row r = 1024: inputs==1 -> t=2, log2(t)=1, term = n_param value itself
    if (blockIdx.z == 0) {
        int j = j0 + tj;
        float np_ = npar[N_IN * (2 * N_OUT) + 2 * j];
        float nn_ = npar[N_IN * (2 * N_OUT) + 2 * j + 1];
        acc += (bp[j] + q) * np_ - (bn[j] + q) * nn_;
    }

    atomicAdd(&out[(b0 + tb) * N_OUT + j0 + tj], 0.5f * acc);
}

extern "C" void kernel_launch(void* const* d_in, const int* in_sizes, int n_in,
                              void* d_out, int out_size, void* d_ws, size_t ws_size,
                              hipStream_t stream) {
    const float* x    = (const float*)d_in[0];
    const float* wp   = (const float*)d_in[1];
    const float* wn   = (const float*)d_in[2];
    const float* bp   = (const float*)d_in[3];
    const float* bn   = (const float*)d_in[4];
    const float* npar = (const float*)d_in[5];
    float* out = (float*)d_out;
    unsigned int* ws = (unsigned int*)d_ws;

    init_ws_kernel<<<1, 1, 0, stream>>>(ws);
    max_kernel<<<512, 256, 0, stream>>>(wp, wn, bp, bn, ws);
    zero_out_kernel<<<256, 256, 0, stream>>>(out);   // out_size = 128*512 = 65536

    dim3 grid(N_OUT / TJ, BDIM / TB, 4);   // 32 x 8 x 4 = 1024 blocks
    memristor_main<<<grid, 256, 0, stream>>>(x, wp, wn, bp, bn, npar, ws, out);
}

// Round 2
// 46.041 us; speedup vs baseline: 1.4500x; 1.4500x over previous
//
#include <hip/hip_runtime.h>

// Memristor dense fwd, algebraically simplified:
//   t[b,r] = max(2*|x[b,r]|, 1e-12);  s = sign(x)
//   q      = max_w / 9  (G_OFF/k_G folded)
//   y[b,j] = 0.5 * [ sum_r s * (2^(log2(t)*gp + log2(wp+q)) - 2^(log2(t)*gn + log2(wn+q)))
//                    + (bp[j]+q)*n_pos[1024,j] - (bn[j]+q)*n_neg[1024,j] ]
// gp/gn = log2(n_param) interleaved columns.

#define N_IN 1024
#define N_OUT 512
#define NB 128
#define Z 32            // r-split
#define RPB 32          // rows per block (N_IN / Z)
#define JT 64           // j tile
#define BT 32           // b tile

__global__ void init_ws_kernel(unsigned int* ws) {
    ws[0] = __float_as_uint(0.5f);   // bias weights participate in max
}

__global__ void max_kernel(const float* __restrict__ wp, const float* __restrict__ wn,
                           const float* __restrict__ bp, const float* __restrict__ bn,
                           unsigned int* __restrict__ ws) {
    const int NW4 = (N_IN * N_OUT) / 4;
    int i = blockIdx.x * blockDim.x + threadIdx.x;
    int stride = gridDim.x * blockDim.x;
    float m = 0.0f;
    const float4* wp4 = (const float4*)wp;
    const float4* wn4 = (const float4*)wn;
    for (int idx = i; idx < NW4; idx += stride) {
        float4 a = wp4[idx];
        float4 b = wn4[idx];
        m = fmaxf(m, fmaxf(fmaxf(a.x, a.y), fmaxf(a.z, a.w)));
        m = fmaxf(m, fmaxf(fmaxf(b.x, b.y), fmaxf(b.z, b.w)));
    }
    if (i < N_OUT) { m = fmaxf(m, bp[i]); m = fmaxf(m, bn[i]); }
    #pragma unroll
    for (int off = 32; off > 0; off >>= 1)
        m = fmaxf(m, __shfl_xor(m, off));
    if ((threadIdx.x & 63) == 0)
        atomicMax(ws, __float_as_uint(m));   // values >= 0: uint order == float order
}

__launch_bounds__(256, 4)
__global__ void memristor_main(const float* __restrict__ x,
                               const float* __restrict__ wp,
                               const float* __restrict__ wn,
                               const float* __restrict__ npar,
                               const unsigned int* __restrict__ wsmax,
                               float* __restrict__ part) {
    // Wg[r][arr][group][4]: arr 0=log2(wp+q) 1=log2(wn+q) 2=gp 3=gn, group XOR-swizzled
    __shared__ float Wg[RPB][4][16][4];   // 32 KiB
    __shared__ float Lx[BT][RPB][2];      // 8 KiB: (log2(t), sign) per (b_local, r)

    const float q = __uint_as_float(wsmax[0]) * (1.0f / 9.0f);

    const int j0 = blockIdx.x * JT;
    const int b0 = blockIdx.y * BT;
    const int rbase = blockIdx.z * RPB;
    const int tid = threadIdx.x;

    // ---------------- staging ----------------
    {
        // x tile: 32 b x 32 r. thread: b_l = tid>>3, r = (tid&7)*4 + k
        int bl = tid >> 3;
        int rq = tid & 7;
        float4 v = *(const float4*)&x[(b0 + bl) * N_IN + rbase + rq * 4];
        float vv[4] = {v.x, v.y, v.z, v.w};
        #pragma unroll
        for (int k = 0; k < 4; ++k) {
            float val = vv[k];
            float s = (val > 0.0f) ? 1.0f : ((val < 0.0f) ? -1.0f : 0.0f);
            float t = fmaxf(2.0f * fabsf(val), 1e-12f);
            Lx[bl][rq * 4 + k][0] = __builtin_amdgcn_logf(t);   // log2
            Lx[bl][rq * 4 + k][1] = s;
        }
    }
    {
        int rr = tid >> 3;            // 0..31
        int cg = tid & 7;             // 0..7, cols cg*8..cg*8+7
        int pg0 = (2 * cg) ^ (rr & 15);
        int pg1 = (2 * cg + 1) ^ (rr & 15);
        // wp / wn -> log2(w+q)
        {
            const float* wrow = &wp[(rbase + rr) * N_OUT + j0 + cg * 8];
            float4 a = *(const float4*)&wrow[0];
            float4 b = *(const float4*)&wrow[4];
            *(float4*)&Wg[rr][0][pg0][0] = make_float4(
                __builtin_amdgcn_logf(a.x + q), __builtin_amdgcn_logf(a.y + q),
                __builtin_amdgcn_logf(a.z + q), __builtin_amdgcn_logf(a.w + q));
            *(float4*)&Wg[rr][0][pg1][0] = make_float4(
                __builtin_amdgcn_logf(b.x + q), __builtin_amdgcn_logf(b.y + q),
                __builtin_amdgcn_logf(b.z + q), __builtin_amdgcn_logf(b.w + q));
        }
        {
            const float* wrow = &wn[(rbase + rr) * N_OUT + j0 + cg * 8];
            float4 a = *(const float4*)&wrow[0];
            float4 b = *(const float4*)&wrow[4];
            *(float4*)&Wg[rr][1][pg0][0] = make_float4(
                __builtin_amdgcn_logf(a.x + q), __builtin_amdgcn_logf(a.y + q),
                __builtin_amdgcn_logf(a.z + q), __builtin_amdgcn_logf(a.w + q));
            *(float4*)&Wg[rr][1][pg1][0] = make_float4(
                __builtin_amdgcn_logf(b.x + q), __builtin_amdgcn_logf(b.y + q),
                __builtin_amdgcn_logf(b.z + q), __builtin_amdgcn_logf(b.w + q));
        }
        // npar: row rbase+rr, cols 2*j0 + cg*16 .. +15 (interleaved pos/neg)
        {
            const float* nrow = &npar[(rbase + rr) * (2 * N_OUT) + 2 * j0 + cg * 16];
            float4 f0 = *(const float4*)&nrow[0];
            float4 f1 = *(const float4*)&nrow[4];
            float4 f2 = *(const float4*)&nrow[8];
            float4 f3 = *(const float4*)&nrow[12];
            *(float4*)&Wg[rr][2][pg0][0] = make_float4(
                __builtin_amdgcn_logf(f0.x), __builtin_amdgcn_logf(f0.z),
                __builtin_amdgcn_logf(f1.x), __builtin_amdgcn_logf(f1.z));
            *(float4*)&Wg[rr][3][pg0][0] = make_float4(
                __builtin_amdgcn_logf(f0.y), __builtin_amdgcn_logf(f0.w),
                __builtin_amdgcn_logf(f1.y), __builtin_amdgcn_logf(f1.w));
            *(float4*)&Wg[rr][2][pg1][0] = make_float4(
                __builtin_amdgcn_logf(f2.x), __builtin_amdgcn_logf(f2.z),
                __builtin_amdgcn_logf(f3.x), __builtin_amdgcn_logf(f3.z));
            *(float4*)&Wg[rr][3][pg1][0] = make_float4(
                __builtin_amdgcn_logf(f2.y), __builtin_amdgcn_logf(f2.w),
                __builtin_amdgcn_logf(f3.y), __builtin_amdgcn_logf(f3.w));
        }
    }
    __syncthreads();

    // ---------------- compute: 2b x 4j micro-tile per thread ----------------
    const int tj4 = tid & 15;        // j group
    const int tb2 = tid >> 4;        // 0..15 -> b pair
    const int bl0 = tb2 * 2;

    float acc0[4] = {0.f, 0.f, 0.f, 0.f};
    float acc1[4] = {0.f, 0.f, 0.f, 0.f};

    #pragma unroll 4
    for (int r = 0; r < RPB; ++r) {
        const float4* wrow = (const float4*)&Wg[r][0][tj4 ^ (r & 15)][0];
        float lwp[4]; *(float4*)lwp = wrow[0];
        float lwn[4]; *(float4*)lwn = wrow[16];
        float gp[4];  *(float4*)gp  = wrow[32];
        float gn[4];  *(float4*)gn  = wrow[48];
        float2 L0 = *(const float2*)&Lx[bl0][r][0];
        float2 L1 = *(const float2*)&Lx[bl0 + 1][r][0];
        #pragma unroll
        for (int jj = 0; jj < 4; ++jj) {
            float ep0 = __builtin_amdgcn_exp2f(fmaf(L0.x, gp[jj], lwp[jj]));
            float en0 = __builtin_amdgcn_exp2f(fmaf(L0.x, gn[jj], lwn[jj]));
            acc0[jj] = fmaf(L0.y, ep0 - en0, acc0[jj]);
            float ep1 = __builtin_amdgcn_exp2f(fmaf(L1.x, gp[jj], lwp[jj]));
            float en1 = __builtin_amdgcn_exp2f(fmaf(L1.x, gn[jj], lwn[jj]));
            acc1[jj] = fmaf(L1.y, ep1 - en1, acc1[jj]);
        }
    }

    float* p0 = &part[(size_t)blockIdx.z * (NB * N_OUT) + (b0 + bl0) * N_OUT + j0 + tj4 * 4];
    *(float4*)&p0[0]     = make_float4(acc0[0], acc0[1], acc0[2], acc0[3]);
    *(float4*)&p0[N_OUT] = make_float4(acc1[0], acc1[1], acc1[2], acc1[3]);
}

__global__ void reduce_kernel(const float* __restrict__ part,
                              const float* __restrict__ bp, const float* __restrict__ bn,
                              const float* __restrict__ npar,
                              const unsigned int* __restrict__ wsmax,
                              float* __restrict__ out) {
    int g = blockIdx.x * blockDim.x + threadIdx.x;   // 0..16383 (float4 index)
    const float4* p4 = (const float4*)part;
    float sx = 0.f, sy = 0.f, sz = 0.f, sw = 0.f;
    #pragma unroll
    for (int z = 0; z < Z; ++z) {
        float4 v = p4[(size_t)z * (NB * N_OUT / 4) + g];
        sx += v.x; sy += v.y; sz += v.z; sw += v.w;
    }
    int o = g * 4;
    int j = o & (N_OUT - 1);
    const float q = __uint_as_float(wsmax[0]) * (1.0f / 9.0f);
    float4 bpv = *(const float4*)&bp[j];
    float4 bnv = *(const float4*)&bn[j];
    const float* nrow = &npar[N_IN * (2 * N_OUT) + 2 * j];
    float4 n0 = *(const float4*)&nrow[0];
    float4 n1 = *(const float4*)&nrow[4];
    sx += (bpv.x + q) * n0.x - (bnv.x + q) * n0.y;
    sy += (bpv.y + q) * n0.z - (bnv.y + q) * n0.w;
    sz += (bpv.z + q) * n1.x - (bnv.z + q) * n1.y;
    sw += (bpv.w + q) * n1.z - (bnv.w + q) * n1.w;
    float4 res = make_float4(0.5f * sx, 0.5f * sy, 0.5f * sz, 0.5f * sw);
    ((float4*)out)[g] = res;
}

extern "C" void kernel_launch(void* const* d_in, const int* in_sizes, int n_in,
                              void* d_out, int out_size, void* d_ws, size_t ws_size,
                              hipStream_t stream) {
    const float* x    = (const float*)d_in[0];
    const float* wp   = (const float*)d_in[1];
    const float* wn   = (const float*)d_in[2];
    const float* bp   = (const float*)d_in[3];
    const float* bn   = (const float*)d_in[4];
    const float* npar = (const float*)d_in[5];
    float* out = (float*)d_out;
    unsigned int* wsmax = (unsigned int*)d_ws;
    float* part = (float*)d_ws + 64;   // 256 B offset, 16B-aligned; Z*65536 floats = 8 MiB

    init_ws_kernel<<<1, 1, 0, stream>>>(wsmax);
    max_kernel<<<256, 256, 0, stream>>>(wp, wn, bp, bn, wsmax);

    dim3 grid(N_OUT / JT, NB / BT, Z);   // 8 x 4 x 32 = 1024 blocks
    memristor_main<<<grid, 256, 0, stream>>>(x, wp, wn, npar, wsmax, part);

    reduce_kernel<<<(NB * N_OUT / 4) / 256, 256, 0, stream>>>(part, bp, bn, npar, wsmax, out);
}